// Round 7
// baseline (190.981 us; speedup 1.0000x reference)
//
#include <hip/hip_runtime.h>

typedef __bf16 bf16;
typedef __bf16 bf16x2 __attribute__((ext_vector_type(2)));
typedef __bf16 bf16x4 __attribute__((ext_vector_type(4)));
typedef __bf16 bf16x8 __attribute__((ext_vector_type(8)));
typedef float f32x4 __attribute__((ext_vector_type(4)));

#define NB 16
#define NC 256
#define NHW 4096
#define NDQ 32
#define NDV 128
#define NM 1024

// ---------------------------------------------------------------------------
// Kernel 0: convert w_qkv (192x256) and w_out (256x128) fp32 -> bf16 once.
// ---------------------------------------------------------------------------
__global__ __launch_bounds__(256) void cvt_weights(const float* __restrict__ wq,
                                                   const float* __restrict__ wo,
                                                   bf16* __restrict__ wq16,
                                                   bf16* __restrict__ wo16) {
    int idx = blockIdx.x * 256 + threadIdx.x;
    const float* src;
    bf16* dst;
    int base;
    if (idx < 6144) { src = wq; dst = wq16; base = idx; }
    else            { src = wo; dst = wo16; base = idx - 6144; }
    float4 a = ((const float4*)src)[base * 2];
    float4 c = ((const float4*)src)[base * 2 + 1];
    bf16x8 v;
    v[0] = (bf16)a.x; v[1] = (bf16)a.y; v[2] = (bf16)a.z; v[3] = (bf16)a.w;
    v[4] = (bf16)c.x; v[5] = (bf16)c.y; v[6] = (bf16)c.z; v[7] = (bf16)c.w;
    *(bf16x8*)&dst[base * 8] = v;
}

// ---------------------------------------------------------------------------
// Kernel 1: qkv via bf16 MFMA + fused maxpool. Paired-row 64n strips.
// Block bx in [0,64): r = bx>>1, half = bx&1 -> covers image rows 2r,2r+1,
// cols [half*32, half*32+32). Local n_loc = g*32 + c  (g = row parity).
// 192 o x 64 n, K=256 in 4 chunks of 64. Grid (64, 16) = 1024 blocks.
// LDS: XS[64][64] + WS[192][64] bf16 swizzled -> 32 KB -> 4 blocks/CU.
// ---------------------------------------------------------------------------
__global__ __launch_bounds__(256) void qkv_mfma(const float* __restrict__ imgs,
                                                const bf16* __restrict__ wq16,
                                                bf16* __restrict__ qT,
                                                bf16* __restrict__ kT,
                                                bf16* __restrict__ vb) {
    __shared__ __align__(16) char lds[32768];
    bf16* XS = (bf16*)lds;             // [64][64] swz, 8 KB
    bf16* WS = (bf16*)(lds + 8192);    // [192][64] swz, 24 KB

    const int tid  = threadIdx.x;
    const int lane = tid & 63;
    const int w    = tid >> 6;
    const int lr   = lane & 15;
    const int lg   = lane >> 4;
    const int bx   = blockIdx.x;
    const int r    = bx >> 1;
    const int half = bx & 1;
    const int b    = blockIdx.y;
    // flat n for local index: n_flat = r*128 + g*64 + half*32 + c
    const int nfb  = r * 128 + half * 32;

    f32x4 acc[3][4];
#pragma unroll
    for (int i = 0; i < 3; i++)
#pragma unroll
        for (int j = 0; j < 4; j++) acc[i][j] = (f32x4){0.f, 0.f, 0.f, 0.f};

    const int snl = tid & 63;          // staging n_loc
    const int sg  = snl >> 5;          // row parity
    const int sc  = snl & 31;          // col within 32
    const int scg = (tid >> 6) * 8;    // staging c-group base (0,8,16,24)

    for (int kc = 0; kc < 4; kc++) {
        if (kc) __syncthreads();
        // ---- stage X: imgs[c][n] -> XS[n_loc][c] bf16, swizzled ----
#pragma unroll
        for (int j = 0; j < 2; j++) {
            int c8 = scg + j * 32;
            const float* g = imgs + (size_t)(b * NC + kc * 64 + c8) * NHW
                             + nfb + sg * 64 + sc;
            bf16x8 v;
#pragma unroll
            for (int i = 0; i < 8; i++) v[i] = (bf16)g[i * NHW];
            *(bf16x8*)(XS + snl * 64 + ((((c8 >> 3) ^ (snl & 7))) << 3)) = v;
        }
        // ---- stage W: wq16[o][kc*64..+64] -> WS[o][c] swz ----
#pragma unroll
        for (int j = 0; j < 6; j++) {
            int idx = j * 256 + tid;      // 0..1535
            int o = idx >> 3, s = idx & 7;
            bf16x8 v = *(const bf16x8*)(wq16 + (size_t)o * NC + kc * 64 + s * 8);
            *(bf16x8*)(WS + o * 64 + ((s ^ (o & 7)) << 3)) = v;
        }
        __syncthreads();
        // ---- compute: 2 sub-k of 32; wave w owns o in [48w, 48w+48) ----
#pragma unroll
        for (int sub = 0; sub < 2; sub++) {
            bf16x8 af[3], bfr[4];
#pragma unroll
            for (int ot = 0; ot < 3; ot++) {
                int o = w * 48 + ot * 16 + lr;
                af[ot] = *(const bf16x8*)(WS + o * 64 + (((sub * 4 + lg) ^ (o & 7)) << 3));
            }
#pragma unroll
            for (int nt = 0; nt < 4; nt++) {
                int n = nt * 16 + lr;
                bfr[nt] = *(const bf16x8*)(XS + n * 64 + (((sub * 4 + lg) ^ (n & 7)) << 3));
            }
#pragma unroll
            for (int ot = 0; ot < 3; ot++)
#pragma unroll
                for (int nt = 0; nt < 4; nt++)
                    acc[ot][nt] = __builtin_amdgcn_mfma_f32_16x16x32_bf16(af[ot], bfr[nt], acc[ot][nt], 0, 0, 0);
        }
    }

    // ---- epilogue: lane holds o = w*48+ot*16+lg*4+rr, n_loc = nt*16+lr ----
    // n_loc -> g = nt>>1, c = (nt&1)*16 + lr
#pragma unroll
    for (int ot = 0; ot < 3; ot++) {
        const int o_base = w * 48 + ot * 16;
        if (o_base < 32) {
            // q: d = o, full resolution
            const int d0 = o_base + lg * 4;
#pragma unroll
            for (int nt = 0; nt < 4; nt++) {
                int n = nfb + (nt >> 1) * 64 + (nt & 1) * 16 + lr;
                bf16x4 v;
#pragma unroll
                for (int rr = 0; rr < 4; rr++) v[rr] = (bf16)acc[ot][nt][rr];
                *(bf16x4*)&qT[((size_t)b * NHW + n) * NDQ + d0] = v;
            }
        } else {
            // pooled: vertical pair nt <-> nt+2, horizontal pair via shfl_xor(1)
            float pm[2][4];
#pragma unroll
            for (int nt = 0; nt < 2; nt++)
#pragma unroll
                for (int rr = 0; rr < 4; rr++) {
                    float v0 = fmaxf(acc[ot][nt][rr], acc[ot][nt + 2][rr]);
                    float v1 = __shfl_xor(v0, 1, 64);
                    pm[nt][rr] = fmaxf(v0, v1);
                }
            if (!(lr & 1)) {
                if (o_base < 64) {
                    const int d0 = o_base - 32 + lg * 4;
#pragma unroll
                    for (int nt = 0; nt < 2; nt++) {
                        int m = r * 32 + half * 16 + nt * 8 + (lr >> 1);
                        bf16x4 v;
#pragma unroll
                        for (int rr = 0; rr < 4; rr++) v[rr] = (bf16)pm[nt][rr];
                        *(bf16x4*)&kT[((size_t)b * NM + m) * NDQ + d0] = v;
                    }
                } else {
                    const int dv0 = o_base - 64 + lg * 4;
#pragma unroll
                    for (int nt = 0; nt < 2; nt++) {
                        int m = r * 32 + half * 16 + nt * 8 + (lr >> 1);
#pragma unroll
                        for (int rr = 0; rr < 4; rr++)
                            vb[((size_t)b * NDV + dv0 + rr) * NM + m] = (bf16)pm[nt][rr];
                    }
                }
            }
        }
    }
}

// ---------------------------------------------------------------------------
// Kernel 2: bf16-MFMA fused attention, QBLK=128, reg-prefetched K/V.
// Grid (32, 16). 4 waves. Per 64-key step:
//   write prefetched K/V regs -> LDS; issue next tile's global loads;
//   QK (8 MFMA/wave) -> exp -> PS;  PV (32 MFMA/wave).
// ---------------------------------------------------------------------------
__global__ __launch_bounds__(256) void attn_mfma(const bf16* __restrict__ qT,
                                                 const bf16* __restrict__ kT,
                                                 const bf16* __restrict__ vb,
                                                 bf16* __restrict__ aT) {
    __shared__ __align__(16) char pool[52224];
    bf16* QT = (bf16*)pool;            // [128][40]  10240 B
    bf16* KT = (bf16*)(pool + 10240);  // [64][40]    5120 B
    bf16* VS = (bf16*)(pool + 15360);  // [128][72]  18432 B
    bf16* PS = (bf16*)(pool + 33792);  // [128][72]  18432 B
    float* DW = (float*)(pool + 33792);

    const int tid  = threadIdx.x;
    const int lane = tid & 63;
    const int w    = tid >> 6;
    const int lr   = lane & 15;
    const int lg   = lane >> 4;
    const int b    = blockIdx.y;
    const int n0   = blockIdx.x * 128;

    // ---- stage QT once: 128 rows x 32 d ----
    {
        const int row = tid >> 1, off = (tid & 1) * 16;
        const bf16* src = qT + (size_t)(b * NHW + n0 + row) * NDQ + off;
        *(bf16x8*)&QT[row * 40 + off]     = *(const bf16x8*)src;
        *(bf16x8*)&QT[row * 40 + off + 8] = *(const bf16x8*)(src + 8);
    }

    // ---- prefetch tile 0 into regs ----
    const int krow = tid >> 2, koff = (tid & 3) * 8;
    const int vrow = tid >> 1, vmb  = (tid & 1) * 32;
    bf16x8 krg, vrg[4];
    krg = *(const bf16x8*)(kT + (size_t)(b * NM + krow) * NDQ + koff);
#pragma unroll
    for (int u = 0; u < 4; u++)
        vrg[u] = *(const bf16x8*)(vb + (size_t)(b * NDV + vrow) * NM + vmb + u * 8);

    __syncthreads();

    // hoisted Q B-frags
    bf16x8 QB[8];
#pragma unroll
    for (int nt = 0; nt < 8; nt++)
        QB[nt] = *(const bf16x8*)&QT[(nt * 16 + lr) * 40 + lg * 8];

    f32x4 zero = {0.f, 0.f, 0.f, 0.f};
    f32x4 acc[2][8];
#pragma unroll
    for (int dt = 0; dt < 2; dt++)
#pragma unroll
        for (int nt = 0; nt < 8; nt++) acc[dt][nt] = zero;
    float denp[8] = {0.f, 0.f, 0.f, 0.f, 0.f, 0.f, 0.f, 0.f};

    for (int t = 0; t < 16; t++) {
        if (t) __syncthreads();    // B1: prev PV done reading VS/PS
        // write prefetched regs to LDS
        *(bf16x8*)&KT[krow * 40 + koff] = krg;
#pragma unroll
        for (int u = 0; u < 4; u++)
            *(bf16x8*)&VS[vrow * 72 + vmb + u * 8] = vrg[u];
        // issue next tile's loads (consumed after next B1 -> latency hidden)
        if (t < 15) {
            const int m1 = (t + 1) * 64;
            krg = *(const bf16x8*)(kT + (size_t)(b * NM + m1 + krow) * NDQ + koff);
#pragma unroll
            for (int u = 0; u < 4; u++)
                vrg[u] = *(const bf16x8*)(vb + (size_t)(b * NDV + vrow) * NM + m1 + vmb + u * 8);
        }
        __syncthreads();           // B2: KT/VS ready

        // ---- QK^T (swapped): wave w owns m-tile w ----
        bf16x8 ka = *(const bf16x8*)&KT[(w * 16 + lr) * 40 + lg * 8];
        f32x4 st[8];
#pragma unroll
        for (int nt = 0; nt < 8; nt++)
            st[nt] = __builtin_amdgcn_mfma_f32_16x16x32_bf16(ka, QB[nt], zero, 0, 0, 0);

        // ---- exp + pack -> PS[n][m] ----
#pragma unroll
        for (int nt = 0; nt < 8; nt++) {
            float e0 = __expf(st[nt][0]);
            float e1 = __expf(st[nt][1]);
            float e2 = __expf(st[nt][2]);
            float e3 = __expf(st[nt][3]);
            denp[nt] += (e0 + e1) + (e2 + e3);
            bf16x4 pv;
            pv[0] = (bf16)e0; pv[1] = (bf16)e1; pv[2] = (bf16)e2; pv[3] = (bf16)e3;
            *(bf16x4*)&PS[(nt * 16 + lr) * 72 + (w * 16 + lg * 4)] = pv;
        }
        __syncthreads();           // B3: PS ready

        // ---- PV: wave w owns d in [32w, 32w+32) ----
#pragma unroll
        for (int mc = 0; mc < 2; mc++) {
            bf16x8 pb[8];
#pragma unroll
            for (int nt = 0; nt < 8; nt++)
                pb[nt] = *(const bf16x8*)&PS[(nt * 16 + lr) * 72 + mc * 32 + lg * 8];
#pragma unroll
            for (int dt = 0; dt < 2; dt++) {
                bf16x8 va = *(const bf16x8*)&VS[(w * 32 + dt * 16 + lr) * 72 + mc * 32 + lg * 8];
#pragma unroll
                for (int nt = 0; nt < 8; nt++)
                    acc[dt][nt] = __builtin_amdgcn_mfma_f32_16x16x32_bf16(va, pb[nt], acc[dt][nt], 0, 0, 0);
            }
        }
    }
    __syncthreads();   // last PV done; PS region reusable for DW

    // ---- denominator reduce ----
#pragma unroll
    for (int nt = 0; nt < 8; nt++) {
        denp[nt] += __shfl_xor(denp[nt], 16, 64);
        denp[nt] += __shfl_xor(denp[nt], 32, 64);
    }
    if (lane < 16) {
#pragma unroll
        for (int nt = 0; nt < 8; nt++) DW[(w * 8 + nt) * 16 + lane] = denp[nt];
    }
    __syncthreads();
    float rinv[8];
#pragma unroll
    for (int nt = 0; nt < 8; nt++) {
        float s = DW[(0 * 8 + nt) * 16 + lr] + DW[(1 * 8 + nt) * 16 + lr] +
                  DW[(2 * 8 + nt) * 16 + lr] + DW[(3 * 8 + nt) * 16 + lr];
        rinv[nt] = 1.0f / s;
    }

    // ---- direct transposed store: aT[n][d] bf16 ----
#pragma unroll
    for (int dt = 0; dt < 2; dt++)
#pragma unroll
        for (int nt = 0; nt < 8; nt++) {
            int d0 = w * 32 + dt * 16 + lg * 4;
            int n  = n0 + nt * 16 + lr;
            bf16x4 v;
#pragma unroll
            for (int rr = 0; rr < 4; rr++) v[rr] = (bf16)(acc[dt][nt][rr] * rinv[nt]);
            *(bf16x4*)&aT[((size_t)b * NHW + n) * NDV + d0] = v;
        }
}

// ---------------------------------------------------------------------------
// Kernel 3: out = imgs + scale * (w_out @ att) via bf16 MFMA. (validated)
// ---------------------------------------------------------------------------
__global__ __launch_bounds__(256) void outproj_mfma(const bf16* __restrict__ aT,
                                                    const bf16* __restrict__ wo16,
                                                    const float* __restrict__ imgs,
                                                    const float* __restrict__ scale_p,
                                                    float* __restrict__ out) {
    __shared__ __align__(16) char lds[65536];
    bf16* XS = (bf16*)lds;             // [128][128] swz, 32 KB
    bf16* WS = (bf16*)(lds + 32768);   // [128][128] swz, 32 KB

    const int tid  = threadIdx.x;
    const int lane = tid & 63;
    const int w    = tid >> 6;
    const int lr   = lane & 15;
    const int lg   = lane >> 4;
    const int wr   = w >> 1, wc = w & 1;
    const int bx   = blockIdx.x;
    const int ch   = blockIdx.y;
    const int b    = blockIdx.z;
    const int n0   = bx * 128;

#pragma unroll
    for (int j = 0; j < 8; j++) {
        int idx = j * 256 + tid;
        int row = idx >> 4, s = idx & 15;
        int sw  = ((s ^ (row & 15)) << 3);
        *(bf16x8*)(XS + row * 128 + sw) =
            *(const bf16x8*)(aT + ((size_t)b * NHW + n0 + row) * NDV + s * 8);
        *(bf16x8*)(WS + row * 128 + sw) =
            *(const bf16x8*)(wo16 + (size_t)(ch * 128 + row) * NDV + s * 8);
    }
    __syncthreads();

    f32x4 acc[4][4];
#pragma unroll
    for (int i = 0; i < 4; i++)
#pragma unroll
        for (int j = 0; j < 4; j++) acc[i][j] = (f32x4){0.f, 0.f, 0.f, 0.f};

#pragma unroll
    for (int kk = 0; kk < 4; kk++) {
        bf16x8 af[4], bfr[4];
#pragma unroll
        for (int ot = 0; ot < 4; ot++) {
            int c = wr * 64 + ot * 16 + lr;
            af[ot] = *(const bf16x8*)(WS + c * 128 + (((kk * 4 + lg) ^ (c & 15)) << 3));
        }
#pragma unroll
        for (int nt = 0; nt < 4; nt++) {
            int n = wc * 64 + nt * 16 + lr;
            bfr[nt] = *(const bf16x8*)(XS + n * 128 + (((kk * 4 + lg) ^ (n & 15)) << 3));
        }
#pragma unroll
        for (int ot = 0; ot < 4; ot++)
#pragma unroll
            for (int nt = 0; nt < 4; nt++)
                acc[ot][nt] = __builtin_amdgcn_mfma_f32_16x16x32_bf16(af[ot], bfr[nt], acc[ot][nt], 0, 0, 0);
    }

    const float sc = *scale_p;
#pragma unroll
    for (int ot = 0; ot < 4; ot++)
#pragma unroll
        for (int nt = 0; nt < 4; nt++) {
            int n = n0 + wc * 64 + nt * 16 + lr;
#pragma unroll
            for (int rr = 0; rr < 4; rr++) {
                int c = ch * 128 + wr * 64 + ot * 16 + lg * 4 + rr;
                size_t off = ((size_t)b * NC + c) * NHW + n;
                out[off] = imgs[off] + sc * acc[ot][nt][rr];
            }
        }
}

extern "C" void kernel_launch(void* const* d_in, const int* in_sizes, int n_in,
                              void* d_out, int out_size, void* d_ws, size_t ws_size,
                              hipStream_t stream) {
    const float* imgs  = (const float*)d_in[0];
    const float* w_qkv = (const float*)d_in[1];
    const float* w_out = (const float*)d_in[2];
    const float* scale = (const float*)d_in[3];
    float* out = (float*)d_out;

    char* wsb = (char*)d_ws;
    bf16* aTg  = (bf16*)(wsb);                       // 16 MiB
    bf16* qTg  = (bf16*)(wsb + (16u << 20));         // 4 MiB
    bf16* kTg  = (bf16*)(wsb + (20u << 20));         // 1 MiB
    bf16* vbg  = (bf16*)(wsb + (21u << 20));         // 4 MiB
    bf16* wq16 = (bf16*)(wsb + (25u << 20));         // 96 KiB
    bf16* wo16 = (bf16*)(wsb + (25u << 20) + 98304); // 64 KiB

    hipLaunchKernelGGL(cvt_weights, dim3(40), dim3(256), 0, stream,
                       w_qkv, w_out, wq16, wo16);
    hipLaunchKernelGGL(qkv_mfma, dim3(64, NB), dim3(256), 0, stream,
                       imgs, wq16, qTg, kTg, vbg);
    hipLaunchKernelGGL(attn_mfma, dim3(32, NB), dim3(256), 0, stream,
                       qTg, kTg, vbg, aTg);
    hipLaunchKernelGGL(outproj_mfma, dim3(32, 2, NB), dim3(256), 0, stream,
                       aTg, wo16, imgs, scale, out);
}